// Round 1
// baseline (350.699 us; speedup 1.0000x reference)
//
#include <hip/hip_runtime.h>

typedef unsigned short u16;
typedef __attribute__((ext_vector_type(8))) short bf16x8;
typedef __attribute__((ext_vector_type(4))) float f32x4;

constexpr int B_ = 4096, IN_ = 512, T_ = 10, E_ = 16, S_ = 2, K_ = 4, W_ = 1024, HD_ = 64;
constexpr int XROW = IN_ + T_;          // 522
constexpr int NPAIR = B_ * K_ + B_ * S_; // 24576

#define GLL16(g, l) __builtin_amdgcn_global_load_lds( \
    (const __attribute__((address_space(1))) void*)(g), \
    (__attribute__((address_space(3))) void*)(l), 16, 0, 0)

__device__ __forceinline__ u16 f2bf(float x) {
    unsigned u = __float_as_uint(x);
    return (u16)((u + 0x7fffu + ((u >> 16) & 1u)) >> 16);
}
__device__ __forceinline__ float bf2f(u16 b) { return __uint_as_float(((unsigned)b) << 16); }

// ---------------- feat fp32 -> bf16 ----------------
__global__ __launch_bounds__(256) void featconv(const float* __restrict__ x, u16* __restrict__ featb) {
    int i = blockIdx.x * 256 + threadIdx.x;      // B_*256 threads, 2 elems each
    int b = i >> 8;
    int c2 = (i & 255) * 2;
    float2 v = *(const float2*)(x + (size_t)b * XROW + c2);
    ushort2 o;
    o.x = f2bf(v.x);
    o.y = f2bf(v.y);
    *(ushort2*)(featb + (size_t)b * IN_ + c2) = o;
}

// ---------------- transpose-convert weights: fp32 [K][N] -> bf16 [N][K] ----------------
__global__ __launch_bounds__(256) void transconv(const float* __restrict__ in, u16* __restrict__ out, int K, int N) {
    __shared__ float tile[32][33];
    int mat = blockIdx.z;
    int k0 = blockIdx.y * 32, n0 = blockIdx.x * 32;
    int tid = threadIdx.x;
    int r = tid >> 3, c4 = (tid & 7) * 4;
    const float* src = in + (size_t)mat * K * N + (size_t)(k0 + r) * N + n0 + c4;
    float4 v = *(const float4*)src;
    tile[r][c4 + 0] = v.x; tile[r][c4 + 1] = v.y; tile[r][c4 + 2] = v.z; tile[r][c4 + 3] = v.w;
    __syncthreads();
    ushort4 ov;
    ov.x = f2bf(tile[c4 + 0][r]);
    ov.y = f2bf(tile[c4 + 1][r]);
    ov.z = f2bf(tile[c4 + 2][r]);
    ov.w = f2bf(tile[c4 + 3][r]);
    *(ushort4*)(out + (size_t)mat * N * K + (size_t)(n0 + r) * K + k0 + c4) = ov;
}

// ---------------- gating: logits, top-4, softmax, task argmax, counts ----------------
__global__ __launch_bounds__(256) void gate_kernel(const float* __restrict__ x, const float* __restrict__ gk,
                                                   int* __restrict__ counts, int* __restrict__ top4i,
                                                   float* __restrict__ w6, int* __restrict__ task_id) {
    int b = blockIdx.x * 256 + threadIdx.x;
    if (b >= B_) return;
    float tv[T_];
#pragma unroll
    for (int i = 0; i < T_; ++i) tv[i] = x[(size_t)b * XROW + IN_ + i];
    float lg[E_];
#pragma unroll
    for (int e = 0; e < E_; ++e) {
        float s = 0.f;
#pragma unroll
        for (int i = 0; i < T_; ++i) s += tv[i] * gk[i * E_ + e];
        lg[e] = s;
    }
    int idx[K_]; float val[K_];
#pragma unroll
    for (int k = 0; k < K_; ++k) {
        int bi = 0; float bv = -1e30f;
#pragma unroll
        for (int e = 0; e < E_; ++e) {
            if (lg[e] > bv) { bv = lg[e]; bi = e; }
        }
        idx[k] = bi; val[k] = bv; lg[bi] = -1e30f;
    }
    float m = val[0];
    float ex[K_]; float s = 0.f;
#pragma unroll
    for (int k = 0; k < K_; ++k) { ex[k] = expf(val[k] - m); s += ex[k]; }
    float inv = 1.f / s;
#pragma unroll
    for (int k = 0; k < K_; ++k) {
        top4i[b * K_ + k] = idx[k];
        w6[b * 6 + k] = ex[k] * inv;
        atomicAdd(&counts[idx[k]], 1);
    }
    w6[b * 6 + 4] = 0.5f;
    w6[b * 6 + 5] = 0.5f;
    int ti = 0; float tb = tv[0];
#pragma unroll
    for (int i = 1; i < T_; ++i) {
        if (tv[i] > tb) { tb = tv[i]; ti = i; }
    }
    task_id[b] = ti;
}

__global__ void prefix16(const int* __restrict__ counts, int* __restrict__ bases) {
    if (threadIdx.x == 0) {
        int a = 0;
        for (int e = 0; e < E_; ++e) { bases[e] = a; a += counts[e]; }
    }
}

__global__ __launch_bounds__(256) void scatter_kernel(const int* __restrict__ top4i, const int* __restrict__ bases,
                                                      int* __restrict__ cursor, int* __restrict__ pair_sample,
                                                      int* __restrict__ pair_dst) {
    int b = blockIdx.x * 256 + threadIdx.x;
    if (b >= B_) return;
#pragma unroll
    for (int k = 0; k < K_; ++k) {
        int e = top4i[b * K_ + k];
        int pos = atomicAdd(&cursor[e], 1);
        int p = bases[e] + pos;
        pair_sample[p] = b;
        pair_dst[p] = b * 6 + k;
    }
    pair_sample[B_ * K_ + b] = b;            pair_dst[B_ * K_ + b] = b * 6 + 4;
    pair_sample[B_ * K_ + B_ + b] = b;       pair_dst[B_ * K_ + B_ + b] = b * 6 + 5;
}

// ---------------- grouped GEMM, 128x128 tile, BK=64, bf16 MFMA ----------------
// LAYER 1: A = featb gathered via pair_sample, K=512, out h1[p]
// LAYER 2: A = h1 rows (pair-ordered), K=1024, out h2[pair_dst[p]]
template <int K, int LAYER>
__global__ __launch_bounds__(256) void gemm_k(const u16* __restrict__ Asrc, const u16* __restrict__ wT,
                                              const float* __restrict__ rbias, const float* __restrict__ sbias,
                                              const int* __restrict__ pair_sample, const int* __restrict__ pair_dst,
                                              const int* __restrict__ bases, const int* __restrict__ counts,
                                              u16* __restrict__ outp) {
    __shared__ char lds[32768];            // A: [128][128B] at 0 ; B: [128][128B] at 16384
    const int tid = threadIdx.x;
    const int e = blockIdx.z, mt = blockIdx.y, nt = blockIdx.x;
    int off, cnt;
    if (e < E_) { off = bases[e]; cnt = counts[e]; }
    else        { off = B_ * K_ + (e - E_) * B_; cnt = B_; }
    if (mt * 128 >= cnt) return;

    const u16* wTe = wT + (size_t)e * W_ * K;
    const float* bias = (e < E_) ? (rbias + (size_t)e * W_) : (sbias + (size_t)(e - E_) * W_);

    // staging: 4 rounds of (256 thr x 16B) per 128x64 tile
    const int srow = tid >> 3;             // 0..31
    const int sc = tid & 7;                // 16B chunk within 128B row
    const u16* abase[4];
    const u16* bbase[4];
#pragma unroll
    for (int r = 0; r < 4; ++r) {
        int row = r * 32 + srow;
        int swz = (sc ^ (row & 7)) * 8;    // inverse-swizzled source (elements)
        int gm = mt * 128 + row;
        if (gm >= cnt) gm = cnt - 1;
        if (LAYER == 1) {
            int smp = pair_sample[off + gm];
            abase[r] = Asrc + (size_t)smp * IN_ + swz;
        } else {
            abase[r] = Asrc + (size_t)(off + gm) * W_ + swz;
        }
        int nrow = nt * 128 + row;
        bbase[r] = wTe + (size_t)nrow * K + swz;
    }
    char* ldsA = lds;
    char* ldsB = lds + 16384;

    f32x4 acc[4][4];
#pragma unroll
    for (int i = 0; i < 4; ++i)
#pragma unroll
        for (int j = 0; j < 4; ++j) acc[i][j] = (f32x4){0.f, 0.f, 0.f, 0.f};

    const int lane = tid & 63;
    const int wid = tid >> 6;
    const int wr = wid >> 1, wc = wid & 1;
    const int fr = lane & 15;
    const int fk = (lane >> 4) * 8;        // k-offset of this lane's fragment

    for (int kt = 0; kt < K / 64; ++kt) {
#pragma unroll
        for (int r = 0; r < 4; ++r) {
            GLL16(abase[r] + kt * 64, ldsA + r * 4096 + tid * 16);
            GLL16(bbase[r] + kt * 64, ldsB + r * 4096 + tid * 16);
        }
        __syncthreads();
#pragma unroll
        for (int kk = 0; kk < 64; kk += 32) {
            bf16x8 af[4], bfr[4];
#pragma unroll
            for (int i = 0; i < 4; ++i) {
                int arow = wr * 64 + i * 16 + fr;
                af[i] = *(const bf16x8*)(ldsA + arow * 128 + (((kk + fk) * 2) ^ ((arow & 7) << 4)));
                int brow = wc * 64 + i * 16 + fr;
                bfr[i] = *(const bf16x8*)(ldsB + brow * 128 + (((kk + fk) * 2) ^ ((brow & 7) << 4)));
            }
#pragma unroll
            for (int i = 0; i < 4; ++i)
#pragma unroll
                for (int j = 0; j < 4; ++j)
                    acc[i][j] = __builtin_amdgcn_mfma_f32_16x16x32_bf16(af[i], bfr[j], acc[i][j], 0, 0, 0);
        }
        __syncthreads();
    }

    // epilogue: bias + relu -> bf16
    const int colbase = nt * 128 + wc * 64;
#pragma unroll
    for (int i = 0; i < 4; ++i) {
#pragma unroll
        for (int reg = 0; reg < 4; ++reg) {
            int rowt = wr * 64 + i * 16 + (lane >> 4) * 4 + reg;
            int m = mt * 128 + rowt;
            if (m < cnt) {
                int outrow = (LAYER == 1) ? (off + m) : pair_dst[off + m];
#pragma unroll
                for (int j = 0; j < 4; ++j) {
                    int col = colbase + j * 16 + fr;
                    float v = acc[i][j][reg] + bias[col];
                    v = fmaxf(v, 0.f);
                    outp[(size_t)outrow * W_ + col] = f2bf(v);
                }
            }
        }
    }
}

// ---------------- combine (tanh of weighted sum) + per-task head ----------------
__global__ __launch_bounds__(256) void combine_head(const u16* __restrict__ h2, const float* __restrict__ w6,
                                                    const int* __restrict__ task_id, const float* __restrict__ hk,
                                                    const float* __restrict__ hb, float* __restrict__ out) {
    __shared__ float f[W_];
    __shared__ float partials[256];
    int b = blockIdx.x, tid = threadIdx.x;
    float wsl[6];
#pragma unroll
    for (int s = 0; s < 6; ++s) wsl[s] = w6[b * 6 + s];
    int t = task_id[b];
    float sum[4] = {0.f, 0.f, 0.f, 0.f};
#pragma unroll
    for (int s = 0; s < 6; ++s) {
        ushort4 v = *(const ushort4*)(h2 + (size_t)(b * 6 + s) * W_ + tid * 4);
        sum[0] += wsl[s] * bf2f(v.x);
        sum[1] += wsl[s] * bf2f(v.y);
        sum[2] += wsl[s] * bf2f(v.z);
        sum[3] += wsl[s] * bf2f(v.w);
    }
#pragma unroll
    for (int i = 0; i < 4; ++i) f[tid * 4 + i] = tanhf(sum[i]);
    __syncthreads();
    int d = tid & 63, g = tid >> 6;
    const float* hkt = hk + (size_t)t * W_ * HD_;
    float acc = 0.f;
#pragma unroll 4
    for (int w = g; w < W_; w += 4) acc += f[w] * hkt[w * HD_ + d];
    partials[tid] = acc;
    __syncthreads();
    if (tid < 64)
        out[(size_t)b * HD_ + tid] =
            partials[tid] + partials[tid + 64] + partials[tid + 128] + partials[tid + 192] + hb[t * HD_ + tid];
}

extern "C" void kernel_launch(void* const* d_in, const int* in_sizes, int n_in,
                              void* d_out, int out_size, void* d_ws, size_t ws_size,
                              hipStream_t stream) {
    const float* x   = (const float*)d_in[0];
    const float* gk  = (const float*)d_in[1];
    const float* rk0 = (const float*)d_in[2];
    const float* rb0 = (const float*)d_in[3];
    const float* rk1 = (const float*)d_in[4];
    const float* rb1 = (const float*)d_in[5];
    const float* sk0 = (const float*)d_in[6];
    const float* sb0 = (const float*)d_in[7];
    const float* sk1 = (const float*)d_in[8];
    const float* sb1 = (const float*)d_in[9];
    const float* hk  = (const float*)d_in[10];
    const float* hb  = (const float*)d_in[11];
    float* out = (float*)d_out;
    (void)in_sizes; (void)n_in; (void)out_size; (void)ws_size;

    char* ws = (char*)d_ws;
    size_t o = 0;
    auto alloc = [&](size_t bytes) { char* p = ws + o; o += (bytes + 255) & ~(size_t)255; return p; };
    int* meta        = (int*)alloc(256);                      // counts[16] | bases[16] | cursor[16]
    int* counts = meta; int* bases = meta + 16; int* cursor = meta + 32;
    int* top4i       = (int*)alloc((size_t)B_ * K_ * 4);
    float* w6        = (float*)alloc((size_t)B_ * 6 * 4);
    int* task_id     = (int*)alloc((size_t)B_ * 4);
    int* pair_sample = (int*)alloc((size_t)NPAIR * 4);
    int* pair_dst    = (int*)alloc((size_t)NPAIR * 4);
    u16* featb       = (u16*)alloc((size_t)B_ * IN_ * 2);
    u16* w0T         = (u16*)alloc((size_t)(E_ + S_) * W_ * IN_ * 2);
    u16* w1T         = (u16*)alloc((size_t)(E_ + S_) * W_ * W_ * 2);
    u16* h1          = (u16*)alloc((size_t)NPAIR * W_ * 2);
    u16* h2          = (u16*)alloc((size_t)NPAIR * W_ * 2);

    hipMemsetAsync(meta, 0, 256, stream);
    featconv<<<B_, 256, 0, stream>>>(x, featb);
    transconv<<<dim3(W_ / 32, IN_ / 32, E_), 256, 0, stream>>>(rk0, w0T, IN_, W_);
    transconv<<<dim3(W_ / 32, IN_ / 32, S_), 256, 0, stream>>>(sk0, w0T + (size_t)E_ * W_ * IN_, IN_, W_);
    transconv<<<dim3(W_ / 32, W_ / 32, E_), 256, 0, stream>>>(rk1, w1T, W_, W_);
    transconv<<<dim3(W_ / 32, W_ / 32, S_), 256, 0, stream>>>(sk1, w1T + (size_t)E_ * W_ * W_, W_, W_);
    gate_kernel<<<B_ / 256, 256, 0, stream>>>(x, gk, counts, top4i, w6, task_id);
    prefix16<<<1, 64, 0, stream>>>(counts, bases);
    scatter_kernel<<<B_ / 256, 256, 0, stream>>>(top4i, bases, cursor, pair_sample, pair_dst);
    gemm_k<IN_, 1><<<dim3(8, 32, E_ + S_), 256, 0, stream>>>(featb, w0T, rb0, sb0, pair_sample, pair_dst, bases, counts, h1);
    gemm_k<W_, 2><<<dim3(8, 32, E_ + S_), 256, 0, stream>>>(h1, w1T, rb1, sb1, pair_sample, pair_dst, bases, counts, h2);
    combine_head<<<B_, 256, 0, stream>>>(h2, w6, task_id, hk, hb, out);
}